// Round 1
// baseline (773.538 us; speedup 1.0000x reference)
//
#include <hip/hip_runtime.h>
#include <hip/hip_bf16.h>

#define N_NODES 50000
#define N_EDGES 800000
#define FD 128
#define N_GRAPHS 256

// ---------------------------------------------------------------- CSR build
__global__ void count_deg_k(const int* __restrict__ src, int* __restrict__ cnt, int E) {
    int e = blockIdx.x * blockDim.x + threadIdx.x;
    if (e < E) atomicAdd(&cnt[src[e]], 1);
}

__global__ __launch_bounds__(1024) void scan_deg_k(const int* __restrict__ cnt,
                                                   int* __restrict__ offs,
                                                   int* __restrict__ cur, int M) {
    const int T = 1024;
    int tid = threadIdx.x;
    int chunk = (M + T - 1) / T;
    int lo = tid * chunk, hi = min(lo + chunk, M);
    int s = 0;
    for (int i = lo; i < hi; i++) s += cnt[i];
    __shared__ int ps[T];
    ps[tid] = s;
    __syncthreads();
    for (int off = 1; off < T; off <<= 1) {
        int v = (tid >= off) ? ps[tid - off] : 0;
        __syncthreads();
        ps[tid] += v;
        __syncthreads();
    }
    int run = (tid > 0) ? ps[tid - 1] : 0;   // exclusive prefix
    for (int i = lo; i < hi; i++) {
        offs[i] = run; cur[i] = run;
        run += cnt[i];
    }
    if (tid == T - 1) offs[M] = run;
}

__global__ void fill_csr_k(const int* __restrict__ src, const int* __restrict__ dst,
                           int* __restrict__ cur, int* __restrict__ col, int E) {
    int e = blockIdx.x * blockDim.x + threadIdx.x;
    if (e < E) {
        int p = atomicAdd(&cur[src[e]], 1);
        col[p] = dst[e];
    }
}

// ---------------------------------------------------------------- GEMM (x*scale+shift) @ W
// A [M,128] row-major, W [128,128] row-major, H [M,128].  BM=128 BN=128 BK=16 TM=8 TN=8.
__global__ __launch_bounds__(256) void gemm_bn_k(const float* __restrict__ X,
                                                 const float* __restrict__ W,
                                                 const float* __restrict__ scale,
                                                 const float* __restrict__ shift,
                                                 float* __restrict__ H, int M) {
    __shared__ float As[16][132];
    __shared__ float Bs[16][128];
    __shared__ float sc[128], sh[128];
    int tid = threadIdx.x;
    if (tid < 128) { sc[tid] = scale[tid]; sh[tid] = shift[tid]; }
    __syncthreads();
    int row0 = blockIdx.x * 128;
    int tc = tid & 15, tr = tid >> 4;
    float acc[8][8];
#pragma unroll
    for (int i = 0; i < 8; i++)
#pragma unroll
        for (int j = 0; j < 8; j++) acc[i][j] = 0.f;

    for (int k0 = 0; k0 < 128; k0 += 16) {
        // A tile: thread loads float4 for rows r, r+64 at k = k0 + (tid&3)*4
        int r = tid >> 2;
        int kk = (tid & 3) * 4;
#pragma unroll
        for (int half = 0; half < 2; half++) {
            int rr = r + half * 64;
            int grow = row0 + rr;
            float4 v = make_float4(0.f, 0.f, 0.f, 0.f);
            if (grow < M) v = *(const float4*)&X[(size_t)grow * FD + k0 + kk];
            v.x = v.x * sc[k0 + kk]     + sh[k0 + kk];
            v.y = v.y * sc[k0 + kk + 1] + sh[k0 + kk + 1];
            v.z = v.z * sc[k0 + kk + 2] + sh[k0 + kk + 2];
            v.w = v.w * sc[k0 + kk + 3] + sh[k0 + kk + 3];
            As[kk][rr] = v.x; As[kk + 1][rr] = v.y; As[kk + 2][rr] = v.z; As[kk + 3][rr] = v.w;
        }
        int kb = tid >> 5;
        int cb = (tid & 31) * 4;
#pragma unroll
        for (int half = 0; half < 2; half++) {
            int kr = kb + half * 8;
            *(float4*)&Bs[kr][cb] = *(const float4*)&W[(size_t)(k0 + kr) * FD + cb];
        }
        __syncthreads();
#pragma unroll
        for (int k = 0; k < 16; k++) {
            float a[8], b[8];
#pragma unroll
            for (int i = 0; i < 8; i++) a[i] = As[k][tr * 8 + i];
#pragma unroll
            for (int j = 0; j < 8; j++) b[j] = Bs[k][tc * 8 + j];
#pragma unroll
            for (int i = 0; i < 8; i++)
#pragma unroll
                for (int j = 0; j < 8; j++) acc[i][j] += a[i] * b[j];
        }
        __syncthreads();
    }
#pragma unroll
    for (int i = 0; i < 8; i++) {
        int grow = row0 + tr * 8 + i;
        if (grow < M) {
            *(float4*)&H[(size_t)grow * FD + tc * 8]     = make_float4(acc[i][0], acc[i][1], acc[i][2], acc[i][3]);
            *(float4*)&H[(size_t)grow * FD + tc * 8 + 4] = make_float4(acc[i][4], acc[i][5], acc[i][6], acc[i][7]);
        }
    }
}

// ---------------------------------------------------------------- per-node attention dots
__global__ void edots_k(const float* __restrict__ H, const float* __restrict__ a,
                        float* __restrict__ es, float* __restrict__ ed, int M) {
    int wave = (blockIdx.x * blockDim.x + threadIdx.x) >> 6;
    int lane = threadIdx.x & 63;
    if (wave >= M) return;
    float2 h2 = *(const float2*)&H[(size_t)wave * FD + lane * 2];
    float ps = h2.x * a[lane * 2] + h2.y * a[lane * 2 + 1];
    float pd = h2.x * a[FD + lane * 2] + h2.y * a[FD + lane * 2 + 1];
#pragma unroll
    for (int o = 32; o > 0; o >>= 1) { ps += __shfl_xor(ps, o); pd += __shfl_xor(pd, o); }
    if (lane == 0) { es[wave] = ps; ed[wave] = pd; }
}

// ---------------------------------------------------------------- aggregation (wave per node)
__global__ __launch_bounds__(256) void agg_k(const float* __restrict__ H,
                                             const float* __restrict__ es_,
                                             const float* __restrict__ ed_,
                                             const int* __restrict__ offs,
                                             const int* __restrict__ col,
                                             float* __restrict__ Out, int M) {
    int wave = (blockIdx.x * blockDim.x + threadIdx.x) >> 6;
    int lane = threadIdx.x & 63;
    if (wave >= M) return;
    int s0 = offs[wave], s1 = offs[wave + 1];
    float es = es_[wave];
    const float2* H2 = (const float2*)H;
    float2 acc = make_float2(0.f, 0.f);
    float rs_l = 0.f;
    for (int base = s0; base < s1; base += 64) {
        int m = s1 - base; if (m > 64) m = 64;
        int d = 0; float eeL = 0.f;
        if (lane < m) {
            d = col[base + lane];
            float e = es + ed_[d];
            float lr = e > 0.f ? e : 0.2f * e;
            eeL = __expf(-lr);
        }
        rs_l += eeL;
#pragma unroll 4
        for (int j = 0; j < m; j++) {
            int dj = __shfl(d, j);
            float ee = __shfl(eeL, j);
            float2 hv = H2[(size_t)dj * 64 + lane];
            acc.x += ee * hv.x;
            acc.y += ee * hv.y;
        }
    }
    float rs = rs_l;
#pragma unroll
    for (int o = 32; o > 0; o >>= 1) rs += __shfl_xor(rs, o);
    float inv = 1.f / (rs + 1e-16f);
    float vx = acc.x * inv, vy = acc.y * inv;
    vx = vx > 0.f ? vx : (__expf(vx) - 1.f);   // elu, alpha=1
    vy = vy > 0.f ? vy : (__expf(vy) - 1.f);
    ((float2*)Out)[(size_t)wave * 64 + lane] = make_float2(vx, vy);
}

// ---------------------------------------------------------------- BN stats / finalize
__global__ void bnstats_k(const float* __restrict__ X, float* __restrict__ sums,
                          float* __restrict__ sumsq, int M) {
    int f = threadIdx.x & 127;
    int half = threadIdx.x >> 7;
    float s1 = 0.f, s2 = 0.f;
    for (int r = blockIdx.x * 2 + half; r < M; r += gridDim.x * 2) {
        float v = X[(size_t)r * FD + f];
        s1 += v; s2 += v * v;
    }
    __shared__ float l1[256], l2[256];
    l1[threadIdx.x] = s1; l2[threadIdx.x] = s2;
    __syncthreads();
    if (half == 0) {
        atomicAdd(&sums[f], l1[f] + l1[f + 128]);
        atomicAdd(&sumsq[f], l2[f] + l2[f + 128]);
    }
}

__global__ void init_affine_k(float* scale, float* shift, float* sums, float* sumsq) {
    int f = threadIdx.x;
    scale[f] = 1.f; shift[f] = 0.f; sums[f] = 0.f; sumsq[f] = 0.f;
}

__global__ void bnfinal_k(float* sums, float* sumsq, const float* __restrict__ g,
                          const float* __restrict__ b, float* scale, float* shift, float invN) {
    int f = threadIdx.x;
    float mu = sums[f] * invN;
    float var = sumsq[f] * invN - mu * mu;
    float sc = g[f] * rsqrtf(var + 1e-5f);
    scale[f] = sc;
    shift[f] = b[f] - mu * sc;
    sums[f] = 0.f; sumsq[f] = 0.f;   // ready for next stats pass
}

// ---------------------------------------------------------------- pooling (sorted graph ids)
__global__ void pool_k(const float* __restrict__ X, const int* __restrict__ gi,
                       float* __restrict__ pooled, int M) {
    int f = threadIdx.x & 127;
    int half = threadIdx.x >> 7;
    int r0 = blockIdx.x * 128 + half;
    int rend = min(blockIdx.x * 128 + 128, M);
    int curg = -1; float acc = 0.f;
    for (int r = r0; r < rend; r += 2) {
        int g = gi[r];
        if (g != curg) {
            if (curg >= 0) atomicAdd(&pooled[(size_t)curg * FD + f], acc);
            curg = g; acc = 0.f;
        }
        acc += X[(size_t)r * FD + f];
    }
    if (curg >= 0) atomicAdd(&pooled[(size_t)curg * FD + f], acc);
}

// ---------------------------------------------------------------- small MLP
__global__ void fc_relu_k(const float* __restrict__ X, const float* __restrict__ Wt,
                          const float* __restrict__ b, float* __restrict__ Y,
                          int K, int Ncols) {
    int g = blockIdx.x;
    int j = threadIdx.x;
    extern __shared__ float xrow[];
    for (int k = threadIdx.x; k < K; k += blockDim.x) xrow[k] = X[(size_t)g * K + k];
    __syncthreads();
    float s = b[j];
    for (int k = 0; k < K; k++) s += xrow[k] * Wt[(size_t)k * Ncols + j];
    Y[(size_t)g * Ncols + j] = fmaxf(s, 0.f);
}

__global__ void fc3_k(const float* __restrict__ X, const float* __restrict__ W,
                      const float* __restrict__ b, float* __restrict__ out) {
    int g = blockIdx.x;
    int l = threadIdx.x;
    float2 x2 = ((const float2*)X)[g * 64 + l];
    float s0 = x2.x * W[(2 * l) * 2]     + x2.y * W[(2 * l + 1) * 2];
    float s1 = x2.x * W[(2 * l) * 2 + 1] + x2.y * W[(2 * l + 1) * 2 + 1];
#pragma unroll
    for (int o = 32; o > 0; o >>= 1) { s0 += __shfl_xor(s0, o); s1 += __shfl_xor(s1, o); }
    if (l == 0) { out[g * 2] = s0 + b[0]; out[g * 2 + 1] = s1 + b[1]; }
}

// ---------------------------------------------------------------- launcher
extern "C" void kernel_launch(void* const* d_in, const int* in_sizes, int n_in,
                              void* d_out, int out_size, void* d_ws, size_t ws_size,
                              hipStream_t stream) {
    const int*   adj  = (const int*)d_in[0];
    const float* xin  = (const float*)d_in[1];
    const int*   gi   = (const int*)d_in[2];
    const float* W1   = (const float*)d_in[4];
    const float* a1   = (const float*)d_in[5];
    const float* bn2g = (const float*)d_in[6];
    const float* bn2b = (const float*)d_in[7];
    const float* W2   = (const float*)d_in[8];
    const float* a2   = (const float*)d_in[9];
    const float* bn3g = (const float*)d_in[10];
    const float* bn3b = (const float*)d_in[11];
    const float* W3   = (const float*)d_in[12];
    const float* a3   = (const float*)d_in[13];
    const float* fc1w = (const float*)d_in[14];
    const float* fc1b = (const float*)d_in[15];
    const float* fc2w = (const float*)d_in[16];
    const float* fc2b = (const float*)d_in[17];
    const float* fc3w = (const float*)d_in[18];
    const float* fc3b = (const float*)d_in[19];
    float* out = (float*)d_out;

    const int N = N_NODES, E = N_EDGES, G = N_GRAPHS;

    float* buf0   = (float*)d_ws;                 // [N,128]
    float* buf1   = buf0 + (size_t)N * FD;        // [N,128]
    float* es     = buf1 + (size_t)N * FD;        // [N]
    float* ed     = es + N;                       // [N]
    float* scale  = ed + N;                       // [128]
    float* shift  = scale + FD;                   // [128]
    float* sums   = shift + FD;                   // [128]
    float* sumsq  = sums + FD;                    // [128]
    float* pooled = sumsq + FD;                   // [G,128]
    float* t1     = pooled + (size_t)G * FD;      // [G,256]
    float* t2     = t1 + (size_t)G * 256;         // [G,128]
    int*   degcnt = (int*)(t2 + (size_t)G * FD);  // [N]
    int*   offs   = degcnt + N;                   // [N+1]
    int*   cur    = offs + (N + 1);               // [N]
    int*   col    = cur + N;                      // [E]

    const int* srcp = adj;
    const int* dstp = adj + E;

    // ---- CSR build (once; reused by all 3 layers)
    hipMemsetAsync(degcnt, 0, (size_t)N * sizeof(int), stream);
    count_deg_k<<<(E + 255) / 256, 256, 0, stream>>>(srcp, degcnt, E);
    scan_deg_k<<<1, 1024, 0, stream>>>(degcnt, offs, cur, N);
    fill_csr_k<<<(E + 255) / 256, 256, 0, stream>>>(srcp, dstp, cur, col, E);
    init_affine_k<<<1, 128, 0, stream>>>(scale, shift, sums, sumsq);

    const int gemm_grid = (N + 127) / 128;
    const int wave_grid = (N + 3) / 4;      // 4 waves per 256-thread block
    const float invN = 1.0f / (float)N;

    // ---- layer 1
    gemm_bn_k<<<gemm_grid, 256, 0, stream>>>(xin, W1, scale, shift, buf0, N);
    edots_k<<<wave_grid, 256, 0, stream>>>(buf0, a1, es, ed, N);
    agg_k<<<wave_grid, 256, 0, stream>>>(buf0, es, ed, offs, col, buf1, N);
    bnstats_k<<<256, 256, 0, stream>>>(buf1, sums, sumsq, N);
    bnfinal_k<<<1, 128, 0, stream>>>(sums, sumsq, bn2g, bn2b, scale, shift, invN);

    // ---- layer 2 (BN fused into GEMM A-load)
    gemm_bn_k<<<gemm_grid, 256, 0, stream>>>(buf1, W2, scale, shift, buf0, N);
    edots_k<<<wave_grid, 256, 0, stream>>>(buf0, a2, es, ed, N);
    agg_k<<<wave_grid, 256, 0, stream>>>(buf0, es, ed, offs, col, buf1, N);
    bnstats_k<<<256, 256, 0, stream>>>(buf1, sums, sumsq, N);
    bnfinal_k<<<1, 128, 0, stream>>>(sums, sumsq, bn3g, bn3b, scale, shift, invN);

    // ---- layer 3
    gemm_bn_k<<<gemm_grid, 256, 0, stream>>>(buf1, W3, scale, shift, buf0, N);
    edots_k<<<wave_grid, 256, 0, stream>>>(buf0, a3, es, ed, N);
    agg_k<<<wave_grid, 256, 0, stream>>>(buf0, es, ed, offs, col, buf1, N);

    // ---- pooling + MLP
    hipMemsetAsync(pooled, 0, (size_t)G * FD * sizeof(float), stream);
    pool_k<<<(N + 127) / 128, 256, 0, stream>>>(buf1, gi, pooled, N);
    fc_relu_k<<<G, 256, FD * sizeof(float), stream>>>(pooled, fc1w, fc1b, t1, FD, 256);
    fc_relu_k<<<G, 128, 256 * sizeof(float), stream>>>(t1, fc2w, fc2b, t2, 256, FD);
    fc3_k<<<G, 64, 0, stream>>>(t2, fc3w, fc3b, out);
}

// Round 2
// 671.506 us; speedup vs baseline: 1.1519x; 1.1519x over previous
//
#include <hip/hip_runtime.h>
#include <hip/hip_bf16.h>

#define N_NODES 50000
#define N_EDGES 800000
#define FD 128
#define N_GRAPHS 256

// ---------------------------------------------------------------- CSR build
__global__ void count_deg_k(const int* __restrict__ src, int* __restrict__ cnt, int E) {
    int e = blockIdx.x * blockDim.x + threadIdx.x;
    if (e < E) atomicAdd(&cnt[src[e]], 1);
}

// Grid-parallel exclusive scan over cnt[0..M) -> offs, cur.  (196 blocks x 256)
__global__ __launch_bounds__(256) void scan1_k(const int* __restrict__ cnt,
                                               int* __restrict__ bsum, int M) {
    int i = blockIdx.x * 256 + threadIdx.x;
    int v = (i < M) ? cnt[i] : 0;
    __shared__ int l[256];
    l[threadIdx.x] = v;
    __syncthreads();
    for (int s = 128; s > 0; s >>= 1) {
        if (threadIdx.x < s) l[threadIdx.x] += l[threadIdx.x + s];
        __syncthreads();
    }
    if (threadIdx.x == 0) bsum[blockIdx.x] = l[0];
}

__global__ __launch_bounds__(256) void scan2_k(int* __restrict__ bsum, int NB) {
    int tid = threadIdx.x;
    int v = (tid < NB) ? bsum[tid] : 0;
    __shared__ int l[256];
    l[tid] = v;
    __syncthreads();
    for (int off = 1; off < 256; off <<= 1) {
        int t = (tid >= off) ? l[tid - off] : 0;
        __syncthreads();
        l[tid] += t;
        __syncthreads();
    }
    if (tid < NB) bsum[tid] = l[tid] - v;   // exclusive
}

__global__ __launch_bounds__(256) void scan3_k(const int* __restrict__ cnt,
                                               const int* __restrict__ bsum,
                                               int* __restrict__ offs,
                                               int* __restrict__ cur, int M) {
    int i = blockIdx.x * 256 + threadIdx.x;
    int tid = threadIdx.x;
    int v = (i < M) ? cnt[i] : 0;
    __shared__ int l[256];
    l[tid] = v;
    __syncthreads();
    for (int off = 1; off < 256; off <<= 1) {
        int t = (tid >= off) ? l[tid - off] : 0;
        __syncthreads();
        l[tid] += t;
        __syncthreads();
    }
    int excl = l[tid] - v + bsum[blockIdx.x];
    if (i < M) { offs[i] = excl; cur[i] = excl; }
    if (i == M - 1) offs[M] = excl + v;
}

__global__ void fill_csr_k(const int* __restrict__ src, const int* __restrict__ dst,
                           int* __restrict__ cur, int* __restrict__ col, int E) {
    int e = blockIdx.x * blockDim.x + threadIdx.x;
    if (e < E) {
        int p = atomicAdd(&cur[src[e]], 1);
        col[p] = dst[e];
    }
}

// ---------------------------------------------------------------- GEMM (x*scale+shift) @ W
// A [M,128] row-major, W [128,128] row-major, H [M,128].  BM=128 BN=128 BK=16 TM=8 TN=8.
__global__ __launch_bounds__(256) void gemm_bn_k(const float* __restrict__ X,
                                                 const float* __restrict__ W,
                                                 const float* __restrict__ scale,
                                                 const float* __restrict__ shift,
                                                 float* __restrict__ H, int M) {
    __shared__ float As[16][132];
    __shared__ float Bs[16][128];
    __shared__ float sc[128], sh[128];
    int tid = threadIdx.x;
    if (tid < 128) { sc[tid] = scale[tid]; sh[tid] = shift[tid]; }
    __syncthreads();
    int row0 = blockIdx.x * 128;
    int tc = tid & 15, tr = tid >> 4;
    float acc[8][8];
#pragma unroll
    for (int i = 0; i < 8; i++)
#pragma unroll
        for (int j = 0; j < 8; j++) acc[i][j] = 0.f;

    for (int k0 = 0; k0 < 128; k0 += 16) {
        int r = tid >> 2;
        int kk = (tid & 3) * 4;
#pragma unroll
        for (int half = 0; half < 2; half++) {
            int rr = r + half * 64;
            int grow = row0 + rr;
            float4 v = make_float4(0.f, 0.f, 0.f, 0.f);
            if (grow < M) v = *(const float4*)&X[(size_t)grow * FD + k0 + kk];
            v.x = v.x * sc[k0 + kk]     + sh[k0 + kk];
            v.y = v.y * sc[k0 + kk + 1] + sh[k0 + kk + 1];
            v.z = v.z * sc[k0 + kk + 2] + sh[k0 + kk + 2];
            v.w = v.w * sc[k0 + kk + 3] + sh[k0 + kk + 3];
            As[kk][rr] = v.x; As[kk + 1][rr] = v.y; As[kk + 2][rr] = v.z; As[kk + 3][rr] = v.w;
        }
        int kb = tid >> 5;
        int cb = (tid & 31) * 4;
#pragma unroll
        for (int half = 0; half < 2; half++) {
            int kr = kb + half * 8;
            *(float4*)&Bs[kr][cb] = *(const float4*)&W[(size_t)(k0 + kr) * FD + cb];
        }
        __syncthreads();
#pragma unroll
        for (int k = 0; k < 16; k++) {
            float a[8], b[8];
#pragma unroll
            for (int i = 0; i < 8; i++) a[i] = As[k][tr * 8 + i];
#pragma unroll
            for (int j = 0; j < 8; j++) b[j] = Bs[k][tc * 8 + j];
#pragma unroll
            for (int i = 0; i < 8; i++)
#pragma unroll
                for (int j = 0; j < 8; j++) acc[i][j] += a[i] * b[j];
        }
        __syncthreads();
    }
#pragma unroll
    for (int i = 0; i < 8; i++) {
        int grow = row0 + tr * 8 + i;
        if (grow < M) {
            *(float4*)&H[(size_t)grow * FD + tc * 8]     = make_float4(acc[i][0], acc[i][1], acc[i][2], acc[i][3]);
            *(float4*)&H[(size_t)grow * FD + tc * 8 + 4] = make_float4(acc[i][4], acc[i][5], acc[i][6], acc[i][7]);
        }
    }
}

// ---------------------------------------------------------------- per-node attention dots
__global__ void edots_k(const float* __restrict__ H, const float* __restrict__ a,
                        float* __restrict__ es, float* __restrict__ ed, int M) {
    int wave = (blockIdx.x * blockDim.x + threadIdx.x) >> 6;
    int lane = threadIdx.x & 63;
    if (wave >= M) return;
    float2 h2 = *(const float2*)&H[(size_t)wave * FD + lane * 2];
    float ps = h2.x * a[lane * 2] + h2.y * a[lane * 2 + 1];
    float pd = h2.x * a[FD + lane * 2] + h2.y * a[FD + lane * 2 + 1];
#pragma unroll
    for (int o = 32; o > 0; o >>= 1) { ps += __shfl_xor(ps, o); pd += __shfl_xor(pd, o); }
    if (lane == 0) { es[wave] = ps; ed[wave] = pd; }
}

// ---------------------------------------------------------------- aggregation (wave per node)
__global__ __launch_bounds__(256) void agg_k(const float* __restrict__ H,
                                             const float* __restrict__ es_,
                                             const float* __restrict__ ed_,
                                             const int* __restrict__ offs,
                                             const int* __restrict__ col,
                                             float* __restrict__ Out, int M) {
    int wave = (blockIdx.x * blockDim.x + threadIdx.x) >> 6;
    int lane = threadIdx.x & 63;
    if (wave >= M) return;
    int s0 = offs[wave], s1 = offs[wave + 1];
    float es = es_[wave];
    const float2* H2 = (const float2*)H;
    float2 acc = make_float2(0.f, 0.f);
    float rs_l = 0.f;
    for (int base = s0; base < s1; base += 64) {
        int m = s1 - base; if (m > 64) m = 64;
        int d = 0; float eeL = 0.f;
        if (lane < m) {
            d = col[base + lane];
            float e = es + ed_[d];
            float lr = e > 0.f ? e : 0.2f * e;
            eeL = __expf(-lr);
        }
        rs_l += eeL;
#pragma unroll 4
        for (int j = 0; j < m; j++) {
            int dj = __shfl(d, j);
            float ee = __shfl(eeL, j);
            float2 hv = H2[(size_t)dj * 64 + lane];
            acc.x += ee * hv.x;
            acc.y += ee * hv.y;
        }
    }
    float rs = rs_l;
#pragma unroll
    for (int o = 32; o > 0; o >>= 1) rs += __shfl_xor(rs, o);
    float inv = 1.f / (rs + 1e-16f);
    float vx = acc.x * inv, vy = acc.y * inv;
    vx = vx > 0.f ? vx : (__expf(vx) - 1.f);   // elu, alpha=1
    vy = vy > 0.f ? vy : (__expf(vy) - 1.f);
    ((float2*)Out)[(size_t)wave * 64 + lane] = make_float2(vx, vy);
}

// ---------------------------------------------------------------- BN stats / finalize
__global__ void bnstats_k(const float* __restrict__ X, float* __restrict__ sums,
                          float* __restrict__ sumsq, int M) {
    int f = threadIdx.x & 127;
    int half = threadIdx.x >> 7;
    float s1 = 0.f, s2 = 0.f;
    for (int r = blockIdx.x * 2 + half; r < M; r += gridDim.x * 2) {
        float v = X[(size_t)r * FD + f];
        s1 += v; s2 += v * v;
    }
    __shared__ float l1[256], l2[256];
    l1[threadIdx.x] = s1; l2[threadIdx.x] = s2;
    __syncthreads();
    if (half == 0) {
        atomicAdd(&sums[f], l1[f] + l1[f + 128]);
        atomicAdd(&sumsq[f], l2[f] + l2[f + 128]);
    }
}

__global__ void init_affine_k(float* scale, float* shift, float* sums, float* sumsq) {
    int f = threadIdx.x;
    scale[f] = 1.f; shift[f] = 0.f; sums[f] = 0.f; sumsq[f] = 0.f;
}

__global__ void bnfinal_k(float* sums, float* sumsq, const float* __restrict__ g,
                          const float* __restrict__ b, float* scale, float* shift, float invN) {
    int f = threadIdx.x;
    float mu = sums[f] * invN;
    float var = sumsq[f] * invN - mu * mu;
    float sc = g[f] * rsqrtf(var + 1e-5f);
    scale[f] = sc;
    shift[f] = b[f] - mu * sc;
    sums[f] = 0.f; sumsq[f] = 0.f;   // ready for next stats pass
}

// ---------------------------------------------------------------- pooling (sorted graph ids)
__global__ void pool_k(const float* __restrict__ X, const int* __restrict__ gi,
                       float* __restrict__ pooled, int M) {
    int f = threadIdx.x & 127;
    int half = threadIdx.x >> 7;
    int r0 = blockIdx.x * 128 + half;
    int rend = min(blockIdx.x * 128 + 128, M);
    int curg = -1; float acc = 0.f;
    for (int r = r0; r < rend; r += 2) {
        int g = gi[r];
        if (g != curg) {
            if (curg >= 0) atomicAdd(&pooled[(size_t)curg * FD + f], acc);
            curg = g; acc = 0.f;
        }
        acc += X[(size_t)r * FD + f];
    }
    if (curg >= 0) atomicAdd(&pooled[(size_t)curg * FD + f], acc);
}

// ---------------------------------------------------------------- small MLP
__global__ void fc_relu_k(const float* __restrict__ X, const float* __restrict__ Wt,
                          const float* __restrict__ b, float* __restrict__ Y,
                          int K, int Ncols) {
    int g = blockIdx.x;
    int j = threadIdx.x;
    extern __shared__ float xrow[];
    for (int k = threadIdx.x; k < K; k += blockDim.x) xrow[k] = X[(size_t)g * K + k];
    __syncthreads();
    float s = b[j];
    for (int k = 0; k < K; k++) s += xrow[k] * Wt[(size_t)k * Ncols + j];
    Y[(size_t)g * Ncols + j] = fmaxf(s, 0.f);
}

__global__ void fc3_k(const float* __restrict__ X, const float* __restrict__ W,
                      const float* __restrict__ b, float* __restrict__ out) {
    int g = blockIdx.x;
    int l = threadIdx.x;
    float2 x2 = ((const float2*)X)[g * 64 + l];
    float s0 = x2.x * W[(2 * l) * 2]     + x2.y * W[(2 * l + 1) * 2];
    float s1 = x2.x * W[(2 * l) * 2 + 1] + x2.y * W[(2 * l + 1) * 2 + 1];
#pragma unroll
    for (int o = 32; o > 0; o >>= 1) { s0 += __shfl_xor(s0, o); s1 += __shfl_xor(s1, o); }
    if (l == 0) { out[g * 2] = s0 + b[0]; out[g * 2 + 1] = s1 + b[1]; }
}

// ---------------------------------------------------------------- launcher
extern "C" void kernel_launch(void* const* d_in, const int* in_sizes, int n_in,
                              void* d_out, int out_size, void* d_ws, size_t ws_size,
                              hipStream_t stream) {
    const int*   adj  = (const int*)d_in[0];
    const float* xin  = (const float*)d_in[1];
    const int*   gi   = (const int*)d_in[2];
    const float* W1   = (const float*)d_in[4];
    const float* a1   = (const float*)d_in[5];
    const float* bn2g = (const float*)d_in[6];
    const float* bn2b = (const float*)d_in[7];
    const float* W2   = (const float*)d_in[8];
    const float* a2   = (const float*)d_in[9];
    const float* bn3g = (const float*)d_in[10];
    const float* bn3b = (const float*)d_in[11];
    const float* W3   = (const float*)d_in[12];
    const float* a3   = (const float*)d_in[13];
    const float* fc1w = (const float*)d_in[14];
    const float* fc1b = (const float*)d_in[15];
    const float* fc2w = (const float*)d_in[16];
    const float* fc2b = (const float*)d_in[17];
    const float* fc3w = (const float*)d_in[18];
    const float* fc3b = (const float*)d_in[19];
    float* out = (float*)d_out;

    const int N = N_NODES, E = N_EDGES, G = N_GRAPHS;

    float* buf0   = (float*)d_ws;                 // [N,128]
    float* buf1   = buf0 + (size_t)N * FD;        // [N,128]
    float* es     = buf1 + (size_t)N * FD;        // [N]
    float* ed     = es + N;                       // [N]
    float* scale  = ed + N;                       // [128]
    float* shift  = scale + FD;                   // [128]
    float* sums   = shift + FD;                   // [128]
    float* sumsq  = sums + FD;                    // [128]
    float* pooled = sumsq + FD;                   // [G,128]
    float* t1     = pooled + (size_t)G * FD;      // [G,256]
    float* t2     = t1 + (size_t)G * 256;         // [G,128]
    int*   degcnt = (int*)(t2 + (size_t)G * FD);  // [N]
    int*   offs   = degcnt + N;                   // [N+1]
    int*   cur    = offs + (N + 1);               // [N]
    int*   col    = cur + N;                      // [E]
    int*   bsum   = col + E;                      // [256]

    const int* srcp = adj;
    const int* dstp = adj + E;

    const int NB = (N + 255) / 256;   // 196

    // ---- CSR build (once; reused by all 3 layers)
    hipMemsetAsync(degcnt, 0, (size_t)N * sizeof(int), stream);
    count_deg_k<<<(E + 255) / 256, 256, 0, stream>>>(srcp, degcnt, E);
    scan1_k<<<NB, 256, 0, stream>>>(degcnt, bsum, N);
    scan2_k<<<1, 256, 0, stream>>>(bsum, NB);
    scan3_k<<<NB, 256, 0, stream>>>(degcnt, bsum, offs, cur, N);
    fill_csr_k<<<(E + 255) / 256, 256, 0, stream>>>(srcp, dstp, cur, col, E);
    init_affine_k<<<1, 128, 0, stream>>>(scale, shift, sums, sumsq);

    const int gemm_grid = (N + 127) / 128;
    const int wave_grid = (N + 3) / 4;      // 4 waves per 256-thread block
    const float invN = 1.0f / (float)N;

    // ---- layer 1
    gemm_bn_k<<<gemm_grid, 256, 0, stream>>>(xin, W1, scale, shift, buf0, N);
    edots_k<<<wave_grid, 256, 0, stream>>>(buf0, a1, es, ed, N);
    agg_k<<<wave_grid, 256, 0, stream>>>(buf0, es, ed, offs, col, buf1, N);
    bnstats_k<<<256, 256, 0, stream>>>(buf1, sums, sumsq, N);
    bnfinal_k<<<1, 128, 0, stream>>>(sums, sumsq, bn2g, bn2b, scale, shift, invN);

    // ---- layer 2 (BN fused into GEMM A-load)
    gemm_bn_k<<<gemm_grid, 256, 0, stream>>>(buf1, W2, scale, shift, buf0, N);
    edots_k<<<wave_grid, 256, 0, stream>>>(buf0, a2, es, ed, N);
    agg_k<<<wave_grid, 256, 0, stream>>>(buf0, es, ed, offs, col, buf1, N);
    bnstats_k<<<256, 256, 0, stream>>>(buf1, sums, sumsq, N);
    bnfinal_k<<<1, 128, 0, stream>>>(sums, sumsq, bn3g, bn3b, scale, shift, invN);

    // ---- layer 3
    gemm_bn_k<<<gemm_grid, 256, 0, stream>>>(buf1, W3, scale, shift, buf0, N);
    edots_k<<<wave_grid, 256, 0, stream>>>(buf0, a3, es, ed, N);
    agg_k<<<wave_grid, 256, 0, stream>>>(buf0, es, ed, offs, col, buf1, N);

    // ---- pooling + MLP
    hipMemsetAsync(pooled, 0, (size_t)G * FD * sizeof(float), stream);
    pool_k<<<(N + 127) / 128, 256, 0, stream>>>(buf1, gi, pooled, N);
    fc_relu_k<<<G, 256, FD * sizeof(float), stream>>>(pooled, fc1w, fc1b, t1, FD, 256);
    fc_relu_k<<<G, 128, 256 * sizeof(float), stream>>>(t1, fc2w, fc2b, t2, 256, FD);
    fc3_k<<<G, 64, 0, stream>>>(t2, fc3w, fc3b, out);
}

// Round 3
// 573.445 us; speedup vs baseline: 1.3489x; 1.1710x over previous
//
#include <hip/hip_runtime.h>
#include <hip/hip_bf16.h>

#define N_NODES 50000
#define N_EDGES 800000
#define FD 128
#define N_GRAPHS 256

// ---------------------------------------------------------------- CSR build
__global__ void count_deg_k(const int* __restrict__ src, int* __restrict__ cnt, int E) {
    int e = blockIdx.x * blockDim.x + threadIdx.x;
    if (e < E) atomicAdd(&cnt[src[e]], 1);
}

// Grid-parallel exclusive scan over cnt[0..M) -> offs, cur.
__global__ __launch_bounds__(256) void scan1_k(const int* __restrict__ cnt,
                                               int* __restrict__ bsum, int M) {
    int i = blockIdx.x * 256 + threadIdx.x;
    int v = (i < M) ? cnt[i] : 0;
    __shared__ int l[256];
    l[threadIdx.x] = v;
    __syncthreads();
    for (int s = 128; s > 0; s >>= 1) {
        if (threadIdx.x < s) l[threadIdx.x] += l[threadIdx.x + s];
        __syncthreads();
    }
    if (threadIdx.x == 0) bsum[blockIdx.x] = l[0];
}

__global__ __launch_bounds__(256) void scan2_k(int* __restrict__ bsum, int NB) {
    int tid = threadIdx.x;
    int v = (tid < NB) ? bsum[tid] : 0;
    __shared__ int l[256];
    l[tid] = v;
    __syncthreads();
    for (int off = 1; off < 256; off <<= 1) {
        int t = (tid >= off) ? l[tid - off] : 0;
        __syncthreads();
        l[tid] += t;
        __syncthreads();
    }
    if (tid < NB) bsum[tid] = l[tid] - v;   // exclusive
}

__global__ __launch_bounds__(256) void scan3_k(const int* __restrict__ cnt,
                                               const int* __restrict__ bsum,
                                               int* __restrict__ offs,
                                               int* __restrict__ cur, int M) {
    int i = blockIdx.x * 256 + threadIdx.x;
    int tid = threadIdx.x;
    int v = (i < M) ? cnt[i] : 0;
    __shared__ int l[256];
    l[tid] = v;
    __syncthreads();
    for (int off = 1; off < 256; off <<= 1) {
        int t = (tid >= off) ? l[tid - off] : 0;
        __syncthreads();
        l[tid] += t;
        __syncthreads();
    }
    int excl = l[tid] - v + bsum[blockIdx.x];
    if (i < M) { offs[i] = excl; cur[i] = excl; }
    if (i == M - 1) offs[M] = excl + v;
}

__global__ void fill_csr_k(const int* __restrict__ src, const int* __restrict__ dst,
                           int* __restrict__ cur, int* __restrict__ col, int E) {
    int e = blockIdx.x * blockDim.x + threadIdx.x;
    if (e < E) {
        int p = atomicAdd(&cur[src[e]], 1);
        col[p] = dst[e];
    }
}

// ---------------------------------------------------------------- GEMM + BN-in + attention dots
// H = (X*scale+shift) @ W ; es = H@a[:128] ; ed = H@a[128:] ; H stored bf16.
__global__ __launch_bounds__(256) void gemm_bn_dots_k(const float* __restrict__ X,
                                                      const float* __restrict__ W,
                                                      const float* __restrict__ scale,
                                                      const float* __restrict__ shift,
                                                      const float* __restrict__ avec,
                                                      __hip_bfloat16* __restrict__ Hb,
                                                      float* __restrict__ es,
                                                      float* __restrict__ ed, int M) {
    __shared__ float As[16][132];
    __shared__ float Bs[16][128];
    __shared__ float sc[128], sh[128], sa_s[128], sa_d[128];
    int tid = threadIdx.x;
    if (tid < 128) {
        sc[tid] = scale[tid]; sh[tid] = shift[tid];
        sa_s[tid] = avec[tid]; sa_d[tid] = avec[128 + tid];
    }
    __syncthreads();
    int row0 = blockIdx.x * 128;
    int tc = tid & 15, tr = tid >> 4;
    float acc[8][8];
#pragma unroll
    for (int i = 0; i < 8; i++)
#pragma unroll
        for (int j = 0; j < 8; j++) acc[i][j] = 0.f;

    for (int k0 = 0; k0 < 128; k0 += 16) {
        int r = tid >> 2;
        int kk = (tid & 3) * 4;
#pragma unroll
        for (int half = 0; half < 2; half++) {
            int rr = r + half * 64;
            int grow = row0 + rr;
            float4 v = make_float4(0.f, 0.f, 0.f, 0.f);
            if (grow < M) v = *(const float4*)&X[(size_t)grow * FD + k0 + kk];
            v.x = v.x * sc[k0 + kk]     + sh[k0 + kk];
            v.y = v.y * sc[k0 + kk + 1] + sh[k0 + kk + 1];
            v.z = v.z * sc[k0 + kk + 2] + sh[k0 + kk + 2];
            v.w = v.w * sc[k0 + kk + 3] + sh[k0 + kk + 3];
            As[kk][rr] = v.x; As[kk + 1][rr] = v.y; As[kk + 2][rr] = v.z; As[kk + 3][rr] = v.w;
        }
        int kb = tid >> 5;
        int cb = (tid & 31) * 4;
#pragma unroll
        for (int half = 0; half < 2; half++) {
            int kr = kb + half * 8;
            *(float4*)&Bs[kr][cb] = *(const float4*)&W[(size_t)(k0 + kr) * FD + cb];
        }
        __syncthreads();
#pragma unroll
        for (int k = 0; k < 16; k++) {
            float a[8], b[8];
#pragma unroll
            for (int i = 0; i < 8; i++) a[i] = As[k][tr * 8 + i];
#pragma unroll
            for (int j = 0; j < 8; j++) b[j] = Bs[k][tc * 8 + j];
#pragma unroll
            for (int i = 0; i < 8; i++)
#pragma unroll
                for (int j = 0; j < 8; j++) acc[i][j] += a[i] * b[j];
        }
        __syncthreads();
    }

    // Epilogue: attention dots (16-lane butterfly over tc) + bf16 store of H.
#pragma unroll
    for (int i = 0; i < 8; i++) {
        int grow = row0 + tr * 8 + i;
        float ps = 0.f, pd = 0.f;
#pragma unroll
        for (int j = 0; j < 8; j++) {
            ps += acc[i][j] * sa_s[tc * 8 + j];
            pd += acc[i][j] * sa_d[tc * 8 + j];
        }
#pragma unroll
        for (int o = 8; o > 0; o >>= 1) { ps += __shfl_xor(ps, o); pd += __shfl_xor(pd, o); }
        if (grow < M) {
            if (tc == 0) { es[grow] = ps; ed[grow] = pd; }
            union { uint4 q; __hip_bfloat16 h[8]; } p;
#pragma unroll
            for (int j = 0; j < 8; j++) p.h[j] = __float2bfloat16(acc[i][j]);
            *(uint4*)&Hb[(size_t)grow * FD + tc * 8] = p.q;
        }
    }
}

// ---------------------------------------------------------------- aggregation (wave per node)
__global__ __launch_bounds__(256) void agg_k(const __hip_bfloat16* __restrict__ Hb,
                                             const float* __restrict__ es_,
                                             const float* __restrict__ ed_,
                                             const int* __restrict__ offs,
                                             const int* __restrict__ col,
                                             float* __restrict__ Out, int M) {
    int wave = (blockIdx.x * blockDim.x + threadIdx.x) >> 6;
    int lane = threadIdx.x & 63;
    if (wave >= M) return;
    int s0 = offs[wave], s1 = offs[wave + 1];
    float es = es_[wave];
    const __hip_bfloat162* H2 = (const __hip_bfloat162*)Hb;
    float2 acc = make_float2(0.f, 0.f);
    float rs_l = 0.f;
    for (int base = s0; base < s1; base += 64) {
        int m = s1 - base; if (m > 64) m = 64;
        int d = 0; float eeL = 0.f;
        if (lane < m) {
            d = col[base + lane];
            float e = es + ed_[d];
            float lr = e > 0.f ? e : 0.2f * e;
            eeL = __expf(-lr);
        }
        rs_l += eeL;
#pragma unroll 8
        for (int j = 0; j < m; j++) {
            int dj = __shfl(d, j);
            float ee = __shfl(eeL, j);
            __hip_bfloat162 hv = H2[(size_t)dj * 64 + lane];
            acc.x += ee * __low2float(hv);
            acc.y += ee * __high2float(hv);
        }
    }
    float rs = rs_l;
#pragma unroll
    for (int o = 32; o > 0; o >>= 1) rs += __shfl_xor(rs, o);
    float inv = 1.f / (rs + 1e-16f);
    float vx = acc.x * inv, vy = acc.y * inv;
    vx = vx > 0.f ? vx : (__expf(vx) - 1.f);   // elu, alpha=1
    vy = vy > 0.f ? vy : (__expf(vy) - 1.f);
    ((float2*)Out)[(size_t)wave * 64 + lane] = make_float2(vx, vy);
}

// ---------------------------------------------------------------- BN stats / finalize
__global__ void bnstats_k(const float* __restrict__ X, float* __restrict__ sums,
                          float* __restrict__ sumsq, int M) {
    int f = threadIdx.x & 127;
    int half = threadIdx.x >> 7;
    float s1 = 0.f, s2 = 0.f;
    for (int r = blockIdx.x * 2 + half; r < M; r += gridDim.x * 2) {
        float v = X[(size_t)r * FD + f];
        s1 += v; s2 += v * v;
    }
    __shared__ float l1[256], l2[256];
    l1[threadIdx.x] = s1; l2[threadIdx.x] = s2;
    __syncthreads();
    if (half == 0) {
        atomicAdd(&sums[f], l1[f] + l1[f + 128]);
        atomicAdd(&sumsq[f], l2[f] + l2[f + 128]);
    }
}

__global__ void init_affine_k(float* scale, float* shift, float* sums, float* sumsq) {
    int f = threadIdx.x;
    scale[f] = 1.f; shift[f] = 0.f; sums[f] = 0.f; sumsq[f] = 0.f;
}

__global__ void bnfinal_k(float* sums, float* sumsq, const float* __restrict__ g,
                          const float* __restrict__ b, float* scale, float* shift, float invN) {
    int f = threadIdx.x;
    float mu = sums[f] * invN;
    float var = sumsq[f] * invN - mu * mu;
    float sc = g[f] * rsqrtf(var + 1e-5f);
    scale[f] = sc;
    shift[f] = b[f] - mu * sc;
    sums[f] = 0.f; sumsq[f] = 0.f;   // ready for next stats pass
}

// ---------------------------------------------------------------- pooling (sorted graph ids)
__global__ void pool_k(const float* __restrict__ X, const int* __restrict__ gi,
                       float* __restrict__ pooled, int M) {
    int f = threadIdx.x & 127;
    int half = threadIdx.x >> 7;
    int r0 = blockIdx.x * 128 + half;
    int rend = min(blockIdx.x * 128 + 128, M);
    int curg = -1; float acc = 0.f;
    for (int r = r0; r < rend; r += 2) {
        int g = gi[r];
        if (g != curg) {
            if (curg >= 0) atomicAdd(&pooled[(size_t)curg * FD + f], acc);
            curg = g; acc = 0.f;
        }
        acc += X[(size_t)r * FD + f];
    }
    if (curg >= 0) atomicAdd(&pooled[(size_t)curg * FD + f], acc);
}

// ---------------------------------------------------------------- small MLP
__global__ void fc_relu_k(const float* __restrict__ X, const float* __restrict__ Wt,
                          const float* __restrict__ b, float* __restrict__ Y,
                          int K, int Ncols) {
    int g = blockIdx.x;
    int j = threadIdx.x;
    extern __shared__ float xrow[];
    for (int k = threadIdx.x; k < K; k += blockDim.x) xrow[k] = X[(size_t)g * K + k];
    __syncthreads();
    float s = b[j];
    for (int k = 0; k < K; k++) s += xrow[k] * Wt[(size_t)k * Ncols + j];
    Y[(size_t)g * Ncols + j] = fmaxf(s, 0.f);
}

__global__ void fc3_k(const float* __restrict__ X, const float* __restrict__ W,
                      const float* __restrict__ b, float* __restrict__ out) {
    int g = blockIdx.x;
    int l = threadIdx.x;
    float2 x2 = ((const float2*)X)[g * 64 + l];
    float s0 = x2.x * W[(2 * l) * 2]     + x2.y * W[(2 * l + 1) * 2];
    float s1 = x2.x * W[(2 * l) * 2 + 1] + x2.y * W[(2 * l + 1) * 2 + 1];
#pragma unroll
    for (int o = 32; o > 0; o >>= 1) { s0 += __shfl_xor(s0, o); s1 += __shfl_xor(s1, o); }
    if (l == 0) { out[g * 2] = s0 + b[0]; out[g * 2 + 1] = s1 + b[1]; }
}

// ---------------------------------------------------------------- launcher
extern "C" void kernel_launch(void* const* d_in, const int* in_sizes, int n_in,
                              void* d_out, int out_size, void* d_ws, size_t ws_size,
                              hipStream_t stream) {
    const int*   adj  = (const int*)d_in[0];
    const float* xin  = (const float*)d_in[1];
    const int*   gi   = (const int*)d_in[2];
    const float* W1   = (const float*)d_in[4];
    const float* a1   = (const float*)d_in[5];
    const float* bn2g = (const float*)d_in[6];
    const float* bn2b = (const float*)d_in[7];
    const float* W2   = (const float*)d_in[8];
    const float* a2   = (const float*)d_in[9];
    const float* bn3g = (const float*)d_in[10];
    const float* bn3b = (const float*)d_in[11];
    const float* W3   = (const float*)d_in[12];
    const float* a3   = (const float*)d_in[13];
    const float* fc1w = (const float*)d_in[14];
    const float* fc1b = (const float*)d_in[15];
    const float* fc2w = (const float*)d_in[16];
    const float* fc2b = (const float*)d_in[17];
    const float* fc3w = (const float*)d_in[18];
    const float* fc3b = (const float*)d_in[19];
    float* out = (float*)d_out;

    const int N = N_NODES, E = N_EDGES, G = N_GRAPHS;

    float* buf1   = (float*)d_ws;                 // [N,128] fp32 (agg out / gemm in)
    __hip_bfloat16* Hb = (__hip_bfloat16*)(buf1 + (size_t)N * FD);  // [N,128] bf16
    float* es     = (float*)(Hb + (size_t)N * FD); // [N]
    float* ed     = es + N;                       // [N]
    float* scale  = ed + N;                       // [128]
    float* shift  = scale + FD;                   // [128]
    float* sums   = shift + FD;                   // [128]
    float* sumsq  = sums + FD;                    // [128]
    float* pooled = sumsq + FD;                   // [G,128]
    float* t1     = pooled + (size_t)G * FD;      // [G,256]
    float* t2     = t1 + (size_t)G * 256;         // [G,128]
    int*   degcnt = (int*)(t2 + (size_t)G * FD);  // [N]
    int*   offs   = degcnt + N;                   // [N+1]
    int*   cur    = offs + (N + 1);               // [N]
    int*   col    = cur + N;                      // [E]
    int*   bsum   = col + E;                      // [256]

    const int* srcp = adj;
    const int* dstp = adj + E;

    const int NB = (N + 255) / 256;   // 196

    // ---- CSR build (once; reused by all 3 layers)
    hipMemsetAsync(degcnt, 0, (size_t)N * sizeof(int), stream);
    count_deg_k<<<(E + 255) / 256, 256, 0, stream>>>(srcp, degcnt, E);
    scan1_k<<<NB, 256, 0, stream>>>(degcnt, bsum, N);
    scan2_k<<<1, 256, 0, stream>>>(bsum, NB);
    scan3_k<<<NB, 256, 0, stream>>>(degcnt, bsum, offs, cur, N);
    fill_csr_k<<<(E + 255) / 256, 256, 0, stream>>>(srcp, dstp, cur, col, E);
    init_affine_k<<<1, 128, 0, stream>>>(scale, shift, sums, sumsq);

    const int gemm_grid = (N + 127) / 128;
    const int wave_grid = (N + 3) / 4;      // 4 waves per 256-thread block
    const float invN = 1.0f / (float)N;

    // ---- layer 1
    gemm_bn_dots_k<<<gemm_grid, 256, 0, stream>>>(xin, W1, scale, shift, a1, Hb, es, ed, N);
    agg_k<<<wave_grid, 256, 0, stream>>>(Hb, es, ed, offs, col, buf1, N);
    bnstats_k<<<256, 256, 0, stream>>>(buf1, sums, sumsq, N);
    bnfinal_k<<<1, 128, 0, stream>>>(sums, sumsq, bn2g, bn2b, scale, shift, invN);

    // ---- layer 2 (BN fused into GEMM A-load)
    gemm_bn_dots_k<<<gemm_grid, 256, 0, stream>>>(buf1, W2, scale, shift, a2, Hb, es, ed, N);
    agg_k<<<wave_grid, 256, 0, stream>>>(Hb, es, ed, offs, col, buf1, N);
    bnstats_k<<<256, 256, 0, stream>>>(buf1, sums, sumsq, N);
    bnfinal_k<<<1, 128, 0, stream>>>(sums, sumsq, bn3g, bn3b, scale, shift, invN);

    // ---- layer 3
    gemm_bn_dots_k<<<gemm_grid, 256, 0, stream>>>(buf1, W3, scale, shift, a3, Hb, es, ed, N);
    agg_k<<<wave_grid, 256, 0, stream>>>(Hb, es, ed, offs, col, buf1, N);

    // ---- pooling + MLP
    hipMemsetAsync(pooled, 0, (size_t)G * FD * sizeof(float), stream);
    pool_k<<<(N + 127) / 128, 256, 0, stream>>>(buf1, gi, pooled, N);
    fc_relu_k<<<G, 256, FD * sizeof(float), stream>>>(pooled, fc1w, fc1b, t1, FD, 256);
    fc_relu_k<<<G, 128, 256 * sizeof(float), stream>>>(t1, fc2w, fc2b, t2, 256, FD);
    fc3_k<<<G, 64, 0, stream>>>(t2, fc3w, fc3b, out);
}